// Round 1
// baseline (357.255 us; speedup 1.0000x reference)
//
#include <hip/hip_runtime.h>

static constexpr int N = 100000;   // nodes
static constexpr int E = 1000000;  // edges
static constexpr int D = 64;       // feature dim (in == out)

// ---- deg[n] = 1.0 (added self loop) --------------------------------------
__global__ __launch_bounds__(256) void k_deg_init(float* __restrict__ deg) {
    int i = blockIdx.x * 256 + threadIdx.x;
    if (i < N) deg[i] = 1.0f;
}

// ---- deg[dst] += 1 for every non-self edge -------------------------------
__global__ __launch_bounds__(256) void k_deg_count(const int* __restrict__ ei,
                                                   float* __restrict__ deg) {
    int i = blockIdx.x * 256 + threadIdx.x;
    if (i < E) {
        int s = ei[i];       // edge_index[0][i] = src
        int t = ei[E + i];   // edge_index[1][i] = dst
        if (s != t) atomicAdd(&deg[t], 1.0f);
    }
}

// ---- dis = deg > 0 ? rsqrt(deg) : 0 (in place) ---------------------------
__global__ __launch_bounds__(256) void k_rsqrt(float* __restrict__ deg) {
    int i = blockIdx.x * 256 + threadIdx.x;
    if (i < N) {
        float v = deg[i];
        deg[i] = v > 0.f ? rsqrtf(v) : 0.f;
    }
}

// ---- h = x @ W^T ----------------------------------------------------------
// One wave per node (lane = output dim o). W staged transposed in LDS so the
// per-k read Wt[k*64 + lane] is lane-consecutive (2 lanes/bank -> free).
// 32 nodes per block so the 16 KB W staging amortizes.
__global__ __launch_bounds__(256) void k_linear(const float* __restrict__ x,
                                                const float* __restrict__ w,
                                                float* __restrict__ h) {
    __shared__ float Wt[D * D];      // Wt[k*64 + o] = w[o*64 + k]
    __shared__ float xs[32 * D];     // 32 staged x rows
    int tid = threadIdx.x;
    for (int i = tid; i < D * D; i += 256) {
        int o = i >> 6, k = i & 63;
        Wt[k * D + o] = w[i];
    }
    int base = blockIdx.x * 32;
    for (int i = tid; i < 32 * D; i += 256) {
        int node = base + (i >> 6);
        xs[i] = (node < N) ? x[node * D + (i & 63)] : 0.f;
    }
    __syncthreads();
    int wave = tid >> 6, lane = tid & 63;
    for (int r = 0; r < 8; ++r) {
        int li = wave * 8 + r;       // local node 0..31 (uniform per wave)
        int node = base + li;
        if (node >= N) break;        // wave-uniform branch
        float acc = 0.f;
#pragma unroll
        for (int k = 0; k < D; ++k)
            acc = fmaf(xs[li * D + k], Wt[k * D + lane], acc);
        h[node * D + lane] = acc;
    }
}

// ---- out[n,d] = dis[n]^2 * h[n,d] + bias[d]  (self-loop message + bias) --
__global__ __launch_bounds__(256) void k_self(const float* __restrict__ h,
                                              const float* __restrict__ dis,
                                              const float* __restrict__ bias,
                                              float* __restrict__ out) {
    int i = blockIdx.x * 256 + threadIdx.x;
    if (i < N * D) {
        int n = i >> 6, d = i & 63;
        float s = dis[n];
        out[i] = s * s * h[i] + bias[d];
    }
}

// ---- edge scatter: out[dst,d] += dis[src]*dis[dst]*h[src,d] --------------
// One wave per edge, lane = dim. Broadcast loads for src/dst/dis, coalesced
// 256 B gather of h[src,:], 64 consecutive-address f32 atomics.
__global__ __launch_bounds__(256) void k_scatter(const int* __restrict__ ei,
                                                 const float* __restrict__ h,
                                                 const float* __restrict__ dis,
                                                 float* __restrict__ out) {
    int i = blockIdx.x * 256 + threadIdx.x;   // over E*64 = 64M (< 2^31)
    int e = i >> 6, d = i & 63;
    if (e < E) {
        int s = ei[e];
        int t = ei[E + e];
        if (s != t) {
            float c = dis[s] * dis[t];
            atomicAdd(&out[t * D + d], c * h[s * D + d]);
        }
    }
}

extern "C" void kernel_launch(void* const* d_in, const int* in_sizes, int n_in,
                              void* d_out, int out_size, void* d_ws, size_t ws_size,
                              hipStream_t stream) {
    const float* x    = (const float*)d_in[0];   // [N, 64]
    const int*   ei   = (const int*)d_in[1];     // [2, E]
    const float* w    = (const float*)d_in[2];   // [64, 64]
    const float* bias = (const float*)d_in[3];   // [64]
    float* out = (float*)d_out;                  // [N, 64]

    float* deg = (float*)d_ws;                   // N floats (becomes dis)
    float* h   = deg + N;                        // N*64 floats (400000 B offset, 16B-aligned)

    k_deg_init <<<(N + 255) / 256, 256, 0, stream>>>(deg);
    k_deg_count<<<(E + 255) / 256, 256, 0, stream>>>(ei, deg);
    k_rsqrt    <<<(N + 255) / 256, 256, 0, stream>>>(deg);
    k_linear   <<<(N + 31) / 32,   256, 0, stream>>>(x, w, h);
    k_self     <<<(N * D + 255) / 256, 256, 0, stream>>>(h, deg, bias, out);
    k_scatter  <<<(E * D) / 256,   256, 0, stream>>>(ei, h, deg, out);
}

// Round 2
// 266.658 us; speedup vs baseline: 1.3397x; 1.3397x over previous
//
#include <hip/hip_runtime.h>

static constexpr int N = 100000;   // nodes
static constexpr int E = 1000000;  // edges
static constexpr int D = 64;       // feature dim (in == out)
static constexpr int NBLK = 98;    // scan blocks (1024 elems each)
static constexpr int PADN = NBLK * 1024;  // 100352, padded for unguarded scan

// ---- cnt[0..PADN) = 0 -----------------------------------------------------
__global__ __launch_bounds__(256) void k_zero(int* __restrict__ cnt) {
    int i = blockIdx.x * 256 + threadIdx.x;
    if (i < PADN) cnt[i] = 0;
}

// ---- cnt[dst] += 1 for every non-self edge --------------------------------
__global__ __launch_bounds__(256) void k_count(const int* __restrict__ ei,
                                               int* __restrict__ cnt) {
    int i = blockIdx.x * 256 + threadIdx.x;
    if (i < E) {
        int s = ei[i];       // src
        int t = ei[E + i];   // dst
        if (s != t) atomicAdd(&cnt[t], 1);
    }
}

// ---- dis[n] = rsqrt(cnt[n] + 1)  (self loop gives deg >= 1) ---------------
__global__ __launch_bounds__(256) void k_rsqrt(const int* __restrict__ cnt,
                                               float* __restrict__ dis) {
    int i = blockIdx.x * 256 + threadIdx.x;
    if (i < N) dis[i] = rsqrtf((float)(cnt[i] + 1));
}

// ---- scan stage 1: per-block (1024 elems) exclusive scan + block total ----
__global__ __launch_bounds__(256) void k_scan1(const int* __restrict__ cnt,
                                               int* __restrict__ row_ptr,
                                               int* __restrict__ partials) {
    __shared__ int s[256];
    int tid = threadIdx.x;
    int base = blockIdx.x * 1024 + tid * 4;
    int4 v = *reinterpret_cast<const int4*>(&cnt[base]);   // padded -> safe
    int tsum = v.x + v.y + v.z + v.w;
    s[tid] = tsum;
    __syncthreads();
    for (int off = 1; off < 256; off <<= 1) {
        int t = (tid >= off) ? s[tid - off] : 0;
        __syncthreads();
        s[tid] += t;
        __syncthreads();
    }
    int run = s[tid] - tsum;   // exclusive prefix of this thread's 4-chunk
    int4 o;
    o.x = run; run += v.x;
    o.y = run; run += v.y;
    o.z = run; run += v.z;
    o.w = run;
    *reinterpret_cast<int4*>(&row_ptr[base]) = o;
    if (tid == 255) partials[blockIdx.x] = s[255];
}

// ---- scan stage 2: exclusive scan of the 98 block totals (one block) ------
__global__ __launch_bounds__(128) void k_scan2(int* __restrict__ partials) {
    __shared__ int s[128];
    int tid = threadIdx.x;
    int v = (tid < NBLK) ? partials[tid] : 0;
    s[tid] = v;
    __syncthreads();
    for (int off = 1; off < 128; off <<= 1) {
        int t = (tid >= off) ? s[tid - off] : 0;
        __syncthreads();
        s[tid] += t;
        __syncthreads();
    }
    if (tid < NBLK) partials[tid] = s[tid] - v;   // exclusive
}

// ---- scan stage 3: add block offsets --------------------------------------
__global__ __launch_bounds__(256) void k_scan3(int* __restrict__ row_ptr,
                                               const int* __restrict__ partials) {
    int i = blockIdx.x * 256 + threadIdx.x;
    if (i < PADN) row_ptr[i] += partials[i >> 10];
}

// ---- fill: srcs[cursor[dst]++] = src (cursor = row_ptr, destroyed) --------
// After this kernel row_ptr[t] == end offset of node t's segment.
__global__ __launch_bounds__(256) void k_fill(const int* __restrict__ ei,
                                              int* __restrict__ row_ptr,
                                              int* __restrict__ srcs) {
    int i = blockIdx.x * 256 + threadIdx.x;
    if (i < E) {
        int s = ei[i];
        int t = ei[E + i];
        if (s != t) {
            int pos = atomicAdd(&row_ptr[t], 1);
            srcs[pos] = s;
        }
    }
}

// ---- h = x @ W^T ----------------------------------------------------------
__global__ __launch_bounds__(256) void k_linear(const float* __restrict__ x,
                                                const float* __restrict__ w,
                                                float* __restrict__ h) {
    __shared__ float Wt[D * D];      // Wt[k*64 + o] = w[o*64 + k]
    __shared__ float xs[32 * D];
    int tid = threadIdx.x;
    for (int i = tid; i < D * D; i += 256) {
        int o = i >> 6, k = i & 63;
        Wt[k * D + o] = w[i];
    }
    int base = blockIdx.x * 32;
    for (int i = tid; i < 32 * D; i += 256) {
        int node = base + (i >> 6);
        xs[i] = (node < N) ? x[node * D + (i & 63)] : 0.f;
    }
    __syncthreads();
    int wave = tid >> 6, lane = tid & 63;
    for (int r = 0; r < 8; ++r) {
        int li = wave * 8 + r;
        int node = base + li;
        if (node >= N) break;        // wave-uniform
        float acc = 0.f;
#pragma unroll
        for (int k = 0; k < D; ++k)
            acc = fmaf(xs[li * D + k], Wt[k * D + lane], acc);
        h[node * D + lane] = acc;
    }
}

// ---- aggregate: one wave per node, CSR gather, registers only -------------
// out[t,:] = dis[t] * ( dis[t]*h[t,:] + sum_j dis[s_j]*h[s_j,:] ) + bias
__global__ __launch_bounds__(256) void k_aggregate(const int* __restrict__ row_ptr,
                                                   const int* __restrict__ srcs,
                                                   const float* __restrict__ dis,
                                                   const float* __restrict__ h,
                                                   const float* __restrict__ bias,
                                                   float* __restrict__ out) {
    int g = blockIdx.x * 256 + threadIdx.x;
    int t = g >> 6, lane = g & 63;
    if (t >= N) return;
    int start = t ? row_ptr[t - 1] : 0;   // row_ptr holds END offsets post-fill
    int end = row_ptr[t];
    float dt = dis[t];
    float acc = dt * h[t * D + lane];     // self-loop message
    for (int j0 = start; j0 < end; j0 += 64) {
        int m = end - j0;
        int   sj = 0;
        float dj = 0.f;
        if (lane < m) {                   // cooperative batch load of srcs+dis
            sj = srcs[j0 + lane];
            dj = dis[sj];
        }
        int iters = m < 64 ? m : 64;
        for (int k = 0; k < iters; ++k) {
            int   s = __shfl(sj, k);
            float c = __shfl(dj, k);
            acc = fmaf(c, h[s * D + lane], acc);
        }
    }
    out[t * D + lane] = fmaf(dt, acc, bias[lane]);
}

extern "C" void kernel_launch(void* const* d_in, const int* in_sizes, int n_in,
                              void* d_out, int out_size, void* d_ws, size_t ws_size,
                              hipStream_t stream) {
    const float* x    = (const float*)d_in[0];   // [N, 64]
    const int*   ei   = (const int*)d_in[1];     // [2, E]
    const float* w    = (const float*)d_in[2];   // [64, 64]
    const float* bias = (const float*)d_in[3];   // [64]
    float* out = (float*)d_out;                  // [N, 64]

    // workspace layout (all 16B-aligned)
    char* ws = (char*)d_ws;
    int*   cnt      = (int*)(ws);                          // PADN ints
    int*   row_ptr  = (int*)(ws + 401408);                 // PADN ints
    int*   partials = (int*)(ws + 802816);                 // 128 ints
    float* dis      = (float*)(ws + 803328);               // N floats
    int*   srcs     = (int*)(ws + 1203328);                // E ints
    float* h        = (float*)(ws + 5203328);              // N*64 floats

    k_zero  <<<PADN / 256, 256, 0, stream>>>(cnt);
    k_count <<<(E + 255) / 256, 256, 0, stream>>>(ei, cnt);
    k_rsqrt <<<(N + 255) / 256, 256, 0, stream>>>(cnt, dis);
    k_scan1 <<<NBLK, 256, 0, stream>>>(cnt, row_ptr, partials);
    k_scan2 <<<1, 128, 0, stream>>>(partials);
    k_scan3 <<<PADN / 256, 256, 0, stream>>>(row_ptr, partials);
    k_fill  <<<(E + 255) / 256, 256, 0, stream>>>(ei, row_ptr, srcs);
    k_linear<<<(N + 31) / 32, 256, 0, stream>>>(x, w, h);
    k_aggregate<<<(N * 64) / 256, 256, 0, stream>>>(row_ptr, srcs, dis, h, bias, out);
}